// Round 3
// baseline (112.152 us; speedup 1.0000x reference)
//
#include <hip/hip_runtime.h>

// WanRotaryPosEmbedS2VStyle: build (cos, sin) RoPE grids.
// out[0..per_out)        = freqs_cos (1, F*60*60, 1, 128) f32
// out[per_out..2*per_out) = freqs_sin
//
// Per element (f, y, x, d):
//   d <  44        -> t_tab[pos][d],   pos = f < num_video_frames ? f : 30
//   44 <= d < 86   -> h_tab[y][d-44]
//   86 <= d < 128  -> w_tab[x][d-86]
//
// Strategy: one block per (y, group-of-4-frames). h/w staging is f-invariant
// so 4 frames amortize it 4x (device staging mem-ops 14.4M -> 2.3M). LDS has
// three 16B-aligned regions (t rows | h row | padded w rows with h40,h41
// prefix so the d=84..87 straddle quad is one aligned b128 read). Main loop:
// branchless ds_read_b128 + two coalesced float4 stores, address updates are
// pure adds.

#define RP_T_DIM 44
#define RP_H_DIM 42
#define RP_W_DIM 42
#define RP_HEAD 128
#define RP_GH 60
#define RP_GW 60
#define RP_FIXED_REF 30
#define RP_FPB 4          // frames per block
#define RP_BLOCK 320      // 5 waves; 1920 quads / 320 = 6 iters exactly

// LDS layout (float indices):
//  [0,176)    : t rows, fl*44 + d (up to 4 rows, 176B stride = 16B mult)
//  [176,218)  : h row (base 176 floats = 704 B, 16B mult)
//  [224,2864) : w rows, 224 + x*44 + {h40, h41, w0..w41} (896 B base, 16B mult)
#define RP_HB 176
#define RP_WB 224
#define RP_LDSF (RP_WB + RP_GW * 44)   // 2864 floats -> 11.46 KB per table

__global__ __launch_bounds__(RP_BLOCK) void wan_rope_kernel(
    const float* __restrict__ t_cos, const float* __restrict__ h_cos,
    const float* __restrict__ w_cos, const float* __restrict__ t_sin,
    const float* __restrict__ h_sin, const float* __restrict__ w_sin,
    const int* __restrict__ nvf_ptr,
    float* __restrict__ out, int sin_offset, int F)
{
    __shared__ __align__(16) float lds_c[RP_LDSF];
    __shared__ __align__(16) float lds_s[RP_LDSF];

    const int tid = threadIdx.x;
    const int y  = blockIdx.x;              // 0..59
    const int f0 = blockIdx.y * RP_FPB;
    const int nf = min(RP_FPB, F - f0);
    const int vpp = nvf_ptr[0];             // num_video_frames (p_t == 1)

    // ---- stage t rows (nf*44 <= 176 elems, single pass)
    if (tid < nf * RP_T_DIM) {
        const int fl = tid / RP_T_DIM;
        const int d  = tid - fl * RP_T_DIM;
        const int ff = f0 + fl;
        const int pos = (ff < vpp) ? ff : RP_FIXED_REF;
        lds_c[tid] = t_cos[pos * RP_T_DIM + d];
        lds_s[tid] = t_sin[pos * RP_T_DIM + d];
    }
    // ---- stage h row
    if (tid < RP_H_DIM) {
        lds_c[RP_HB + tid] = h_cos[y * RP_H_DIM + tid];
        lds_s[RP_HB + tid] = h_sin[y * RP_H_DIM + tid];
    }
    // ---- w-row prefixes: replicate h40,h41 (120 slots)
    if (tid < 2 * RP_GW) {
        const int x = tid >> 1, j = tid & 1;
        lds_c[RP_WB + x * 44 + j] = h_cos[y * RP_H_DIM + 40 + j];
        lds_s[RP_WB + x * 44 + j] = h_sin[y * RP_H_DIM + 40 + j];
    }
    // ---- w table body (2520 contiguous, coalesced)
    for (int i = tid; i < RP_GW * RP_W_DIM; i += RP_BLOCK) {
        const int x = i / RP_W_DIM;
        const int j = i - x * RP_W_DIM;
        lds_c[RP_WB + x * 44 + 2 + j] = w_cos[i];
        lds_s[RP_WB + x * 44 + 2 + j] = w_sin[i];
    }
    __syncthreads();

    const int q  = tid & 31;   // quad index within head dim (fixed per thread)
    const int xb = tid >> 5;   // 0..9; x = it*10 + xb

    // LDS read address per lane (all 16B aligned):
    //   q < 11       : t region, 4q   (+44 per frame)
    //   11 <= q < 21 : h region, 132 + 4q          (invariant)
    //   q >= 21      : w region, 140 + 44x + 4q    (+440 per it)
    //     q==21 reads {h40,h41,w0,w1} = d 84..87 straddle.
    const bool is_t = q < 11;
    const int lidx0 = is_t ? (q << 2)
                    : ((q < 21) ? (132 + (q << 2))
                                : (140 + 44 * xb + (q << 2)));
    const int finc = is_t ? RP_T_DIM : 0;
    const int winc = (q >= 21) ? 440 : 0;

    int base_f = (f0 * (RP_GH * RP_GW) + y * RP_GW + xb) * RP_HEAD + (q << 2);

    for (int fl = 0; fl < nf; ++fl) {
        int lidx = lidx0 + fl * finc;
        int base = base_f;
#pragma unroll
        for (int it = 0; it < 6; ++it) {
            const float4 c = *(const float4*)(lds_c + lidx);
            const float4 s = *(const float4*)(lds_s + lidx);
            *(float4*)(out + base) = c;
            *(float4*)(out + sin_offset + base) = s;
            lidx += winc;
            base += 10 * RP_HEAD;
        }
        base_f += RP_GH * RP_GW * RP_HEAD;
    }
}

extern "C" void kernel_launch(void* const* d_in, const int* in_sizes, int n_in,
                              void* d_out, int out_size, void* d_ws, size_t ws_size,
                              hipStream_t stream) {
    // Input order: hidden_states, freq_t_cos, freq_h_cos, freq_w_cos,
    // freq_t_sin, freq_h_sin, freq_w_sin, num_video_frames, num_ref_frames.
    const float* t_cos = (const float*)d_in[1];
    const float* h_cos = (const float*)d_in[2];
    const float* w_cos = (const float*)d_in[3];
    const float* t_sin = (const float*)d_in[4];
    const float* h_sin = (const float*)d_in[5];
    const float* w_sin = (const float*)d_in[6];
    const int*   nvf   = (const int*)d_in[7];
    float* out = (float*)d_out;

    // hidden_states (1,16,22,120,120), patch (1,2,2) -> 60x60 grid.
    // out_size = 2 * F * 3600 * 128 -> derive F (no D2H sync).
    const int per_out = out_size / 2;
    const int F = per_out / (RP_GH * RP_GW * RP_HEAD);

    dim3 block(RP_BLOCK);
    dim3 grid(RP_GH, (F + RP_FPB - 1) / RP_FPB);   // (y, frame-group)
    wan_rope_kernel<<<grid, block, 0, stream>>>(
        t_cos, h_cos, w_cos, t_sin, h_sin, w_sin, nvf, out, per_out, F);
}